// Round 2
// baseline (701.993 us; speedup 1.0000x reference)
//
#include <hip/hip_runtime.h>

#define HIDDEN   64
#define SKIP_CH  256
#define T_LEN    32768
#define B_N      8
#define TILE_T   64
#define PAD      64   // DILATION * (KERNEL - 1)

__device__ __forceinline__ float fast_rcp(float x) { return __builtin_amdgcn_rcpf(x); }
__device__ __forceinline__ float fast_tanh(float x) {
    // 1 - 2/(1+e^{2x}); saturates correctly at +-1 via rcp(inf)=0
    return 1.0f - 2.0f * fast_rcp(1.0f + __expf(2.0f * x));
}
__device__ __forceinline__ float fast_sigmoid(float x) {
    return fast_rcp(1.0f + __expf(-x));
}

// Fused: causal dilated conv (K=2, dil=64) + bias + cond + tanh*sigmoid gate
//        + 1x1 skip conv (256) + 1x1 out conv (64) + residual.
// Block: 512 threads = 8 waves; lanes = 64 t-columns; tile = 64 t per block.
// LDS 48KB -> 3 blocks/CU (24 waves/CU); launch_bounds(512,6) keeps VGPR<=~80.
__global__ __launch_bounds__(512, 6)
void resblock_kernel(const float* __restrict__ sig,   // [B][64][T]
                     const float* __restrict__ cond,  // [B][128][T]
                     const float* __restrict__ Wd,    // [128][64][2]
                     const float* __restrict__ bd,    // [128]
                     const float* __restrict__ Wo,    // [64][64]
                     const float* __restrict__ bo,    // [64]
                     const float* __restrict__ Ws,    // [256][64]
                     const float* __restrict__ bs,    // [256]
                     float* __restrict__ out,         // [B][64][T]
                     float* __restrict__ skip)        // [B][256][T]
{
    __shared__ float s_sig[64 * 128];   // [c][tt], tt = t - t0 + 64   (32 KB)
    __shared__ float s_g[64 * 64];      // [h][lane]                   (16 KB)

    const int tid  = threadIdx.x;
    const int lane = tid & 63;
    const int w    = __builtin_amdgcn_readfirstlane(tid >> 6);  // wave id, scalar

    const int t0 = blockIdx.x * TILE_T;
    const int b  = blockIdx.y;
    const int t  = t0 + lane;

    const float* sigB  = sig  + (size_t)b * HIDDEN * T_LEN;
    const float* condB = cond + (size_t)b * (2 * HIDDEN) * T_LEN;

    // ---- stage signal tile [64][128] = cols t0-64 .. t0+63, zero-pad t<0 ----
    {
        const int base_t = t0 - PAD;
        #pragma unroll
        for (int i = 0; i < 4; ++i) {
            int idx4 = i * 512 + tid;          // float4 index, 0..2047
            int c    = idx4 >> 5;              // 32 float4 per row
            int tt   = (idx4 & 31) << 2;
            int gt   = base_t + tt;
            float4 v = make_float4(0.f, 0.f, 0.f, 0.f);
            if (gt >= 0)
                v = *reinterpret_cast<const float4*>(sigB + (size_t)c * T_LEN + gt);
            *reinterpret_cast<float4*>(&s_sig[c * 128 + tt]) = v;
        }
    }
    __syncthreads();

    // ---- phase 1: dilated conv + bias + cond + gate -> s_g ----
    // 8 waves x 2 iters x 4 h-values = 64 gated channels
    #pragma unroll
    for (int it = 0; it < 2; ++it) {
        const int h0 = (w * 2 + it) * 4;       // wave-uniform
        float acc[8];
        #pragma unroll
        for (int j = 0; j < 4; ++j) {
            acc[j]     = bd[h0 + j]      + condB[(size_t)(h0 + j)      * T_LEN + t];
            acc[4 + j] = bd[h0 + j + 64] + condB[(size_t)(h0 + j + 64) * T_LEN + t];
        }
        const float* Wr0 = Wd + h0 * 128;         // rows h0..h0+3, [c][k] contiguous
        const float* Wr1 = Wd + (h0 + 64) * 128;  // rows h0+64..h0+67
        #pragma unroll 4
        for (int c = 0; c < 64; ++c) {
            float s0 = s_sig[c * 128 + lane];        // t-64 tap
            float s1 = s_sig[c * 128 + 64 + lane];   // t tap
            #pragma unroll
            for (int j = 0; j < 4; ++j) {
                acc[j]     += Wr0[j * 128 + 2 * c] * s0 + Wr0[j * 128 + 2 * c + 1] * s1;
                acc[4 + j] += Wr1[j * 128 + 2 * c] * s0 + Wr1[j * 128 + 2 * c + 1] * s1;
            }
        }
        #pragma unroll
        for (int j = 0; j < 4; ++j) {
            float g = fast_tanh(acc[j]) * fast_sigmoid(acc[4 + j]);
            s_g[(h0 + j) * 64 + lane] = g;
        }
    }
    __syncthreads();

    // ---- phase 2: 320 output rows (256 skip + 64 out), 40 rows per wave ----
    const size_t outBase  = (size_t)b * HIDDEN  * T_LEN;
    const size_t skipBase = (size_t)b * SKIP_CH * T_LEN;
    #pragma unroll
    for (int rb = 0; rb < 5; ++rb) {
        const int r0 = w * 40 + rb * 8;        // wave-uniform; never straddles 256
        const bool is_skip = (r0 < 256);
        const float* Wbase = is_skip ? (Ws + r0 * 64) : (Wo + (r0 - 256) * 64);
        const float* bias  = is_skip ? (bs + r0)      : (bo + (r0 - 256));
        float acc[8];
        #pragma unroll
        for (int j = 0; j < 8; ++j) acc[j] = bias[j];
        #pragma unroll 4
        for (int c = 0; c < 64; ++c) {
            float g = s_g[c * 64 + lane];
            #pragma unroll
            for (int j = 0; j < 8; ++j)
                acc[j] += Wbase[j * 64 + c] * g;
        }
        if (is_skip) {
            #pragma unroll
            for (int j = 0; j < 8; ++j)
                skip[skipBase + (size_t)(r0 + j) * T_LEN + t] = acc[j];
        } else {
            #pragma unroll
            for (int j = 0; j < 8; ++j) {
                int oo = r0 - 256 + j;
                out[outBase + (size_t)oo * T_LEN + t] =
                    acc[j] + s_sig[oo * 128 + 64 + lane];   // + residual from LDS
            }
        }
    }
}

extern "C" void kernel_launch(void* const* d_in, const int* in_sizes, int n_in,
                              void* d_out, int out_size, void* d_ws, size_t ws_size,
                              hipStream_t stream) {
    const float* sig  = (const float*)d_in[0];
    const float* cond = (const float*)d_in[1];
    const float* Wd   = (const float*)d_in[2];
    const float* bd   = (const float*)d_in[3];
    const float* Wo   = (const float*)d_in[4];
    const float* bo   = (const float*)d_in[5];
    const float* Ws   = (const float*)d_in[6];
    const float* bs   = (const float*)d_in[7];

    float* out  = (float*)d_out;                                    // [8][64][32768]
    float* skip = (float*)d_out + (size_t)B_N * HIDDEN * T_LEN;     // [8][256][32768]

    dim3 grid(T_LEN / TILE_T, B_N);
    resblock_kernel<<<grid, 512, 0, stream>>>(sig, cond, Wd, bd, Wo, bo, Ws, bs, out, skip);
}